// Round 10
// baseline (188.705 us; speedup 1.0000x reference)
//
#include <hip/hip_runtime.h>

// R-GCN basis-decomposed layer, fissioned:
//   k_agg1: 1 wave/node gather+combine -> aggb bf16 (pre-swizzled rows),
//           scalar col path, 2-deep gather pipeline
//   k_gemm: out = aggb @ BtT via mfma 16x16x32 bf16, BM=128, BK=64,
//           triple-buffered LDS, counted-vmcnt (12/6/0) pipeline
// Fallback (small ws): fused kernel (swizzled-Bt reader).
//
// ws path A (~145.9 MB): featbf | Bt | aggb | deg | rp | col | blksum
// ws path B (~22.7 MB):  featbf | Bt | deg | rp | col | blksum

namespace {
constexpr int kN     = 30000;
constexpr int kR0    = 8;
constexpr int kNRel  = 16;
constexpr int kIN    = 256;
constexpr int kOUT   = 256;
constexpr int kE     = 300000;
constexpr int kNB    = 8;
constexpr int kKT    = kNB * kIN;          // 2048
constexpr int kRows  = kN * kNRel;         // 480000
constexpr int kMsgs  = 2 * kE;             // 600000
constexpr int kScanBlk  = 1024;
constexpr int kNScanBlk = (kRows + kScanBlk - 1) / kScanBlk;   // 469
constexpr int kBM    = 128;
constexpr int kMB    = (kN + kBM - 1) / kBM;   // 235 gemm blocks
constexpr int kMPadAlloc = 30016;              // aggb alloc rows (as round 9; last
                                               // block over-reads into csr: harmless)
constexpr int kTN    = 16;                 // fused-path nodes per block
}

typedef __bf16 bf16x8 __attribute__((ext_vector_type(8)));
typedef float  f32x4  __attribute__((ext_vector_type(4)));
typedef float  f32x2  __attribute__((ext_vector_type(2)));
typedef float  f32x4v __attribute__((ext_vector_type(4)));
typedef unsigned int u32;

static __device__ __forceinline__ ushort f2bf(float x) {
  unsigned u = __float_as_uint(x);
  u += 0x7FFF + ((u >> 16) & 1);           // round-to-nearest-even
  return (ushort)(u >> 16);
}

static __device__ __forceinline__ void gload16(const void* g, void* l) {
  __builtin_amdgcn_global_load_lds(
      (const __attribute__((address_space(1))) u32*)g,
      (__attribute__((address_space(3))) u32*)l, 16, 0, 0);
}

// acc.lo += C.lo*G.lo ; acc.hi += C.lo*G.hi   (broadcast C low half)
#define PKFMA_LO(ACC, G, C) \
  asm("v_pk_fma_f32 %0, %1, %2, %0 op_sel_hi:[1,0,1]" : "+v"(ACC) : "v"(G), "v"(C))
// acc.lo += C.hi*G.lo ; acc.hi += C.hi*G.hi   (broadcast C high half)
#define PKFMA_HI(ACC, G, C) \
  asm("v_pk_fma_f32 %0, %1, %2, %0 op_sel:[0,1,0] op_sel_hi:[1,1,1]" : "+v"(ACC) : "v"(G), "v"(C))

// ---------------- prep: bf16 feature copy + degree count + Bt build (merged) ----------------

__global__ void k_prep(const float* __restrict__ f, ushort* __restrict__ fb,
                       const int* __restrict__ t, int* __restrict__ deg,
                       const float* __restrict__ bases, ushort* __restrict__ Bt) {
  int i = blockIdx.x * 256 + threadIdx.x;
  if (i < kN * kIN / 4) {
    float4 v = reinterpret_cast<const float4*>(f)[i];
    ushort4 p;
    p.x = f2bf(v.x); p.y = f2bf(v.y); p.z = f2bf(v.z); p.w = f2bf(v.w);
    reinterpret_cast<ushort4*>(fb)[i] = p;
  }
  if (i < kE) {
    int s = t[3*i], r = t[3*i+1], o = t[3*i+2];
    atomicAdd(&deg[s * kNRel + r], 1);
    atomicAdd(&deg[o * kNRel + kR0 + r], 1);
  }
  if (blockIdx.x < kKT / 16) {             // 128 blocks handle the Bt transpose
    int b  = blockIdx.x;                   // k-block [b*16, b*16+16)
    int tt = threadIdx.x;                  // 256 = output col
    char* dst = (char*)Bt + (size_t)tt * 4096;
    int xr = (tt & 7) << 4;
#pragma unroll
    for (int q = 0; q < 4; ++q) {
      int k0 = b * 16 + q * 4;
      ushort4 p;
      p.x = f2bf(bases[(size_t)(k0 + 0) * kOUT + tt]);
      p.y = f2bf(bases[(size_t)(k0 + 1) * kOUT + tt]);
      p.z = f2bf(bases[(size_t)(k0 + 2) * kOUT + tt]);
      p.w = f2bf(bases[(size_t)(k0 + 3) * kOUT + tt]);
      *reinterpret_cast<ushort4*>(dst + ((b * 32 + q * 8) ^ xr)) = p;
    }
  }
}

// ---------------- CSR build ----------------

__global__ void k_scan1(const int* __restrict__ deg, int* __restrict__ rp,
                        int* __restrict__ blksum) {
  __shared__ int s[256];
  int tid = threadIdx.x;
  int base = blockIdx.x * kScanBlk + tid * 4;
  int v0 = 0, v1 = 0, v2 = 0, v3 = 0;
  if (base + 3 < kRows) {
    v0 = deg[base]; v1 = deg[base+1]; v2 = deg[base+2]; v3 = deg[base+3];
  } else {
    if (base     < kRows) v0 = deg[base];
    if (base + 1 < kRows) v1 = deg[base+1];
    if (base + 2 < kRows) v2 = deg[base+2];
  }
  int t0 = v0, t1 = t0 + v1, t2 = t1 + v2, t3 = t2 + v3;
  s[tid] = t3;
  __syncthreads();
  for (int off = 1; off < 256; off <<= 1) {
    int x = 0;
    if (tid >= off) x = s[tid - off];
    __syncthreads();
    s[tid] += x;
    __syncthreads();
  }
  int excl = tid ? s[tid-1] : 0;
  if (base     < kRows) rp[base]   = excl;
  if (base + 1 < kRows) rp[base+1] = excl + t0;
  if (base + 2 < kRows) rp[base+2] = excl + t1;
  if (base + 3 < kRows) rp[base+3] = excl + t2;
  if (tid == 255) blksum[blockIdx.x] = s[255];
}

// merged scan2+scan3: each block reduces blksum[0..region) itself, then adds.
__global__ void k_scan3(int* __restrict__ rp, const int* __restrict__ blksum) {
  __shared__ int red[256];
  int tid = threadIdx.x;
  int B   = blockIdx.x;
  int region = (B * 256) >> 10;
  int partial = 0;
  for (int k = tid; k < region; k += 256) partial += blksum[k];
  red[tid] = partial;
  __syncthreads();
#pragma unroll
  for (int off = 128; off > 0; off >>= 1) {
    if (tid < off) red[tid] += red[tid + off];
    __syncthreads();
  }
  int base = red[0];
  int i = B * 256 + tid;
  if (i < kRows)       rp[i] += base;
  else if (i == kRows) rp[i]  = kMsgs;
}

// cursor = atomicSub on the still-live deg counts (no second memset needed)
__global__ void k_scatter(const int* __restrict__ t, const int* __restrict__ rp,
                          int* __restrict__ deg, int* __restrict__ col) {
  int m = blockIdx.x * 256 + threadIdx.x;
  if (m >= kMsgs) return;
  int e = (m < kE) ? m : m - kE;
  int s = t[3*e], r = t[3*e+1], o = t[3*e+2];
  int rr, tn, sn;
  if (m < kE) { rr = r;        tn = s; sn = o; }
  else        { rr = kR0 + r;  tn = o; sn = s; }
  int idx = tn * kNRel + rr;
  int pos = rp[idx] + (atomicSub(&deg[idx], 1) - 1);
  col[pos] = (rr << 16) | sn;
}

#define FMA4(A, S, G) \
  A.x += (S) * G.x; A.y += (S) * G.y; A.z += (S) * G.z; A.w += (S) * G.w;

// ---------------- path A stage 1: one wave per node, scalar cols, 2-deep pipeline ----------------

__global__ __launch_bounds__(256, 6)
void k_agg1(const int* __restrict__ rp, const int* __restrict__ col,
            const ushort* __restrict__ featbf, const float* __restrict__ comps,
            ushort* __restrict__ aggb) {
  __shared__ float cvb[4][17][kNB];     // per-wave coeff table, row 16 = zeros
  int wv   = threadIdx.x >> 6;
  int lane = threadIdx.x & 63;
  int node = blockIdx.x * 4 + wv;       // kN % 4 == 0

  if (lane < 17) {
    float val = 0.f;
    if (lane < kNRel) {
      int idx = node * kNRel + lane;
      int d = rp[idx + 1] - rp[idx];
      val = d > 0 ? 1.0f / (float)d : 0.f;
    }
#pragma unroll
    for (int b = 0; b < kNB; ++b)
      cvb[wv][lane][b] = comps[lane * kNB + b] * val;
  }
  __syncthreads();

  int se0 = __builtin_amdgcn_readfirstlane(rp[node * kNRel]);
  int se1 = __builtin_amdgcn_readfirstlane(rp[node * kNRel + kNRel]);

  // self-loop init (relation 16, val = 1) from bf16 features
  f32x2 accp[2 * kNB];                  // accp[2b]=ch01, accp[2b+1]=ch23 of basis b
  {
    uint2 sf = *reinterpret_cast<const uint2*>(featbf + (size_t)node * kIN + lane * 4);
    f32x2 p01, p23;
    p01.x = __uint_as_float(sf.x << 16);
    p01.y = __uint_as_float(sf.x & 0xFFFF0000u);
    p23.x = __uint_as_float(sf.y << 16);
    p23.y = __uint_as_float(sf.y & 0xFFFF0000u);
#pragma unroll
    for (int b = 0; b < kNB; ++b) {
      float cs = comps[2*kR0*kNB + b];
      accp[2*b]     = p01 * cs;
      accp[2*b + 1] = p23 * cs;
    }
  }

  const int pad = (16 << 16);           // rel slot 16 -> zero coeffs, node 0 row
  int voff = lane * 4;                  // element offset within a feature row
  const f32x4v* cvr = reinterpret_cast<const f32x4v*>(&cvb[wv][0][0]);

  auto loadcols = [&](int base, int* sc) {
#pragma unroll
    for (int j = 0; j < 4; ++j) {
      int ee = base + j;
      int ic = ee < se1 ? ee : 0;
      int v  = col[ic];
      sc[j] = ee < se1 ? v : pad;
    }
  };
  auto gath = [&](const int* sc, uint2* g) {
#pragma unroll
    for (int j = 0; j < 4; ++j)
      g[j] = *reinterpret_cast<const uint2*>(
          featbf + (size_t)(sc[j] & 0xFFFF) * kIN + voff);
  };
  auto compute = [&](const uint2* g, const int* sc) {
#pragma unroll
    for (int j = 0; j < 4; ++j) {
      int sr = sc[j] >> 16;
      f32x4v cA = cvr[sr * 2];
      f32x4v cB = cvr[sr * 2 + 1];
      f32x2 p01, p23;
      p01.x = __uint_as_float(g[j].x << 16);
      p01.y = __uint_as_float(g[j].x & 0xFFFF0000u);
      p23.x = __uint_as_float(g[j].y << 16);
      p23.y = __uint_as_float(g[j].y & 0xFFFF0000u);
      f32x2 cAl = cA.lo, cAh = cA.hi, cBl = cB.lo, cBh = cB.hi;
      PKFMA_LO(accp[0],  p01, cAl); PKFMA_LO(accp[1],  p23, cAl);   // b0
      PKFMA_HI(accp[2],  p01, cAl); PKFMA_HI(accp[3],  p23, cAl);   // b1
      PKFMA_LO(accp[4],  p01, cAh); PKFMA_LO(accp[5],  p23, cAh);   // b2
      PKFMA_HI(accp[6],  p01, cAh); PKFMA_HI(accp[7],  p23, cAh);   // b3
      PKFMA_LO(accp[8],  p01, cBl); PKFMA_LO(accp[9],  p23, cBl);   // b4
      PKFMA_HI(accp[10], p01, cBl); PKFMA_HI(accp[11], p23, cBl);   // b5
      PKFMA_LO(accp[12], p01, cBh); PKFMA_LO(accp[13], p23, cBh);   // b6
      PKFMA_HI(accp[14], p01, cBh); PKFMA_HI(accp[15], p23, cBh);   // b7
    }
  };

  // 2-deep pipeline: chunk i computed in iter i; its gathers issued in iter i-2
  int sc0[4], sc1[4], sc2[4];
  uint2 g0[4], g1[4];
  loadcols(se0,     sc0); gath(sc0, g0);
  loadcols(se0 + 4, sc1); gath(sc1, g1);
  loadcols(se0 + 8, sc2);

#pragma unroll 2
  for (int e = se0; e < se1; e += 4) {
    uint2 g2[4];
    gath(sc2, g2);                      // chunk i+2 gathers (pad-safe)
    int sc3[4];
    loadcols(e + 12, sc3);              // chunk i+3 cols
    compute(g0, sc0);                   // chunk i (loads issued 2 iters ago)
#pragma unroll
    for (int j = 0; j < 4; ++j) {
      g0[j] = g1[j]; g1[j] = g2[j];
      sc0[j] = sc1[j]; sc1[j] = sc2[j]; sc2[j] = sc3[j];
    }
  }

  // write bf16 row, pre-swizzled so GEMM's linear global_load_lds lands swizzled
  char* rowp = (char*)aggb + (size_t)node * 4096;
  int xr = (node & 7) << 4;
#pragma unroll
  for (int b = 0; b < kNB; ++b) {
    ushort4 p;
    p.x = f2bf(accp[2*b].x);     p.y = f2bf(accp[2*b].y);
    p.z = f2bf(accp[2*b + 1].x); p.w = f2bf(accp[2*b + 1].y);
    *reinterpret_cast<ushort4*>(rowp + ((b * 512 + lane * 8) ^ xr)) = p;
  }
}

// ---------------- path A stage 2: BM=128 MFMA GEMM, triple-buffered counted-vmcnt ----------------
// Per chunk/wave: 6 global_load_lds (2 A + 4 B). Two chunks prefetched ahead:
// wait vmcnt(12) -> chunk c landed while c+1, c+2 stay in flight.

__global__ __launch_bounds__(512, 2)
void k_gemm(const ushort* __restrict__ aggb, const ushort* __restrict__ Bt,
            const float* __restrict__ bias, float* __restrict__ out) {
  __shared__ ushort Albs[3][kBM * 64];     // 3 x 16 KB, row stride 128 B (swizzled)
  __shared__ ushort Blds[3][256 * 64];     // 3 x 32 KB, row stride 128 B (swizzled)
  int tid  = threadIdx.x;
  int wv   = tid >> 6;          // 0..7
  int lane = tid & 63;
  int mh   = wv >> 2;           // 0..1 : rows [mh*64, +64)
  int nq   = wv & 3;            // 0..3 : cols [nq*64, +64)
  int l15  = lane & 15;
  int g4   = lane >> 4;
  int node0 = blockIdx.x * kBM;

  f32x4 acc[4][4];
#pragma unroll
  for (int mt = 0; mt < 4; ++mt)
#pragma unroll
    for (int nt = 0; nt < 4; ++nt) acc[mt][nt] = f32x4{0.f, 0.f, 0.f, 0.f};

  auto stage = [&](int c, int buf) {
#pragma unroll
    for (int i = 0; i < 2; ++i) {   // A: 16 KB = 16 segs of 1 KB, 2 per wave
      int seg = wv * 2 + i;
      int lin = seg * 1024 + lane * 16;
      int row = lin >> 7;
      const char* src = (const char*)aggb + (size_t)(node0 + row) * 4096
                        + c * 128 + (lin & 127);
      gload16(src, (char*)Albs[buf] + seg * 1024);
    }
#pragma unroll
    for (int i = 0; i < 4; ++i) {   // B: 32 KB = 32 segs, 4 per wave
      int seg = wv * 4 + i;
      int lin = seg * 1024 + lane * 16;
      int colr = lin >> 7;
      const char* src = (const char*)Bt + (size_t)colr * 4096
                        + c * 128 + (lin & 127);
      gload16(src, (char*)Blds[buf] + seg * 1024);
    }
  };

  stage(0, 0);
  stage(1, 1);

  for (int c = 0; c < 32; ++c) {
    int cur = c % 3;
    if (c + 2 < 32) {
      stage(c + 2, (c + 2) % 3);                   // keep 2 chunks in flight
      asm volatile("s_waitcnt vmcnt(12)" ::: "memory");  // chunk c landed (own wave)
    } else if (c + 1 < 32) {
      asm volatile("s_waitcnt vmcnt(6)" ::: "memory");
    } else {
      asm volatile("s_waitcnt vmcnt(0)" ::: "memory");
    }
    __builtin_amdgcn_s_barrier();                  // all waves' chunk-c loads landed
    __builtin_amdgcn_sched_barrier(0);
#pragma unroll
    for (int ks = 0; ks < 2; ++ks) {
      int kb = ks * 64 + g4 * 16;
      bf16x8 a[4], b[4];
#pragma unroll
      for (int mt = 0; mt < 4; ++mt) {
        int row = mh * 64 + mt * 16 + l15;
        a[mt] = *reinterpret_cast<const bf16x8*>(
            (const char*)Albs[cur] + row * 128 + (kb ^ ((row & 7) << 4)));
      }
#pragma unroll
      for (int nt = 0; nt < 4; ++nt) {
        int colr = nq * 64 + nt * 16 + l15;
        b[nt] = *reinterpret_cast<const bf16x8*>(
            (const char*)Blds[cur] + colr * 128 + (kb ^ ((colr & 7) << 4)));
      }
#pragma unroll
      for (int mt = 0; mt < 4; ++mt)
#pragma unroll
        for (int nt = 0; nt < 4; ++nt)
          acc[mt][nt] = __builtin_amdgcn_mfma_f32_16x16x32_bf16(a[mt], b[nt],
                                                                acc[mt][nt], 0, 0, 0);
    }
    asm volatile("s_waitcnt lgkmcnt(0)" ::: "memory");   // LDS reads of cur done
    __builtin_amdgcn_s_barrier();                  // before anyone re-stages cur
  }

#pragma unroll
  for (int nt = 0; nt < 4; ++nt) {
    int colo = nq * 64 + nt * 16 + l15;
    float bi = bias[colo];
#pragma unroll
    for (int mt = 0; mt < 4; ++mt) {
      int rbase = node0 + mh * 64 + mt * 16 + g4 * 4;
#pragma unroll
      for (int j = 0; j < 4; ++j) {
        int row = rbase + j;
        if (row < kN) out[(size_t)row * kOUT + colo] = acc[mt][nt][j] + bi;
      }
    }
  }
}

// ---------------- path B: fused fallback (swizzled-Bt reader) ----------------

__global__ __launch_bounds__(512, 4)
void k_out_fused(const int* __restrict__ rp, const int* __restrict__ col,
                 const float* __restrict__ feat, const ushort* __restrict__ featbf,
                 const ushort* __restrict__ Bt, const float* __restrict__ comps,
                 const float* __restrict__ bias, float* __restrict__ out) {
  __shared__ ushort aggs[kTN * kKT];
  __shared__ float  cvb[kTN][17][kNB];
  int tid  = threadIdx.x;
  int wv   = tid >> 6;
  int lane = tid & 63;
  int node0 = blockIdx.x * kTN;

  for (int q = tid; q < kTN * 17; q += 512) {
    int nl = q / 17, rl = q - nl * 17;
    float val = 0.f;
    if (rl < kNRel) {
      int idx = (node0 + nl) * kNRel + rl;
      int d = rp[idx + 1] - rp[idx];
      val = d > 0 ? 1.0f / (float)d : 0.f;
    }
#pragma unroll
    for (int b = 0; b < kNB; ++b)
      cvb[nl][rl][b] = comps[rl * kNB + b] * val;
  }
  __syncthreads();

  for (int half = 0; half < 2; ++half) {
    int nl   = (wv << 1) | half;
    int node = node0 + nl;
    int e0 = rp[node * kNRel];
    int e1 = rp[node * kNRel + kNRel];

    float4 f = *reinterpret_cast<const float4*>(feat + (size_t)node * kIN + lane * 4);
    float4 acc[kNB];
#pragma unroll
    for (int b = 0; b < kNB; ++b) {
      float cs = comps[2*kR0*kNB + b];
      acc[b].x = cs * f.x; acc[b].y = cs * f.y; acc[b].z = cs * f.z; acc[b].w = cs * f.w;
    }
    const float4* cvr = reinterpret_cast<const float4*>(&cvb[nl][0][0]);
    const int pad = (16 << 16);
    int cc[4];
#pragma unroll
    for (int j = 0; j < 4; ++j) {
      int ee = e0 + j;
      int v  = col[ee < kMsgs ? ee : kMsgs - 1];
      cc[j] = ee < e1 ? v : pad;
    }
    for (int e = e0; e < e1; e += 4) {
      uint2 g[4];
#pragma unroll
      for (int j = 0; j < 4; ++j) {
        int sn = cc[j] & 0xFFFF;
        g[j] = *reinterpret_cast<const uint2*>(featbf + (size_t)sn * kIN + lane * 4);
      }
      int rr[4];
#pragma unroll
      for (int j = 0; j < 4; ++j) rr[j] = cc[j] >> 16;
#pragma unroll
      for (int j = 0; j < 4; ++j) {
        int ee = e + 4 + j;
        int v  = col[ee < kMsgs ? ee : kMsgs - 1];
        cc[j] = ee < e1 ? v : pad;
      }
#pragma unroll
      for (int j = 0; j < 4; ++j) {
        float4 c0 = cvr[rr[j] * 2];
        float4 c1 = cvr[rr[j] * 2 + 1];
        float4 gg;
        gg.x = __uint_as_float(g[j].x << 16);
        gg.y = __uint_as_float(g[j].x & 0xFFFF0000u);
        gg.z = __uint_as_float(g[j].y << 16);
        gg.w = __uint_as_float(g[j].y & 0xFFFF0000u);
        FMA4(acc[0], c0.x, gg) FMA4(acc[1], c0.y, gg)
        FMA4(acc[2], c0.z, gg) FMA4(acc[3], c0.w, gg)
        FMA4(acc[4], c1.x, gg) FMA4(acc[5], c1.y, gg)
        FMA4(acc[6], c1.z, gg) FMA4(acc[7], c1.w, gg)
      }
    }
    int xr = (nl & 7) << 4;
#pragma unroll
    for (int b = 0; b < kNB; ++b) {
      ushort4 p;
      p.x = f2bf(acc[b].x); p.y = f2bf(acc[b].y);
      p.z = f2bf(acc[b].z); p.w = f2bf(acc[b].w);
      int byteoff = nl * 4096 + ((b * 512 + lane * 8) ^ xr);
      *reinterpret_cast<ushort4*>(reinterpret_cast<char*>(aggs) + byteoff) = p;
    }
  }
  __syncthreads();

  {
    int n  = lane & 15;
    int g4 = lane >> 4;
    const char* abase = reinterpret_cast<const char*>(aggs) + n * 4096;
    int axor = (n & 7) << 4;
#pragma unroll
    for (int t = 0; t < 2; ++t) {
      int ntile = wv + t * 8;
      float bi = bias[ntile * 16 + n];
      const char* btrow = reinterpret_cast<const char*>(Bt)
                          + (size_t)(ntile * 16 + n) * 4096;
      int bxor = (n & 7) << 4;
      f32x4 acc = {0.f, 0.f, 0.f, 0.f};
#pragma unroll 4
      for (int ks = 0; ks < kKT / 32; ++ks) {
        int kb = ks * 64 + g4 * 16;
        bf16x8 af = *reinterpret_cast<const bf16x8*>(abase + (kb ^ axor));
        bf16x8 bf = *reinterpret_cast<const bf16x8*>(btrow + (kb ^ bxor));
        acc = __builtin_amdgcn_mfma_f32_16x16x32_bf16(af, bf, acc, 0, 0, 0);
      }
#pragma unroll
      for (int j = 0; j < 4; ++j) {
        int row = g4 * 4 + j;
        out[(size_t)(node0 + row) * kOUT + ntile * 16 + n] = acc[j] + bi;
      }
    }
  }
}

// ---------------- launch ----------------

extern "C" void kernel_launch(void* const* d_in, const int* in_sizes, int n_in,
                              void* d_out, int out_size, void* d_ws, size_t ws_size,
                              hipStream_t stream) {
  const int*   triples = (const int*)  d_in[0];
  const float* feat    = (const float*)d_in[1];
  const float* bases   = (const float*)d_in[2];
  const float* comps   = (const float*)d_in[3];
  const float* bias    = (const float*)d_in[4];
  float* out = (float*)d_out;

  size_t featbf_b = (size_t)kN * kIN * 2;          // 15,360,000
  size_t bt_b     = (size_t)kOUT * kKT * 2;        // 1,048,576
  size_t aggb_b   = (size_t)kMPadAlloc * kKT * 2;  // 122,945,536
  size_t csr_b    = (size_t)(kRows + kRows + 1 + kMsgs + kNScanBlk) * 4;
  bool bigws = ws_size >= featbf_b + bt_b + aggb_b + csr_b + 1024;

  char* p = (char*)d_ws;
  ushort* featbf = (ushort*)p;            p += featbf_b;
  ushort* Bt     = (ushort*)p;            p += bt_b;
  ushort* aggb   = nullptr;
  if (bigws) { aggb = (ushort*)p;         p += aggb_b; }
  int* deg    = (int*)p;
  int* rp     = deg + kRows;
  int* col    = rp + kRows + 1;
  int* blksum = col + kMsgs;

  hipMemsetAsync(deg, 0, kRows * sizeof(int), stream);
  k_prep  <<<(kN * kIN / 4 + 255) / 256, 256, 0, stream>>>(feat, featbf, triples, deg,
                                                           bases, Bt);
  k_scan1 <<<kNScanBlk,             256, 0, stream>>>(deg, rp, blksum);
  k_scan3 <<<(kRows + 256) / 256,   256, 0, stream>>>(rp, blksum);
  k_scatter<<<(kMsgs + 255) / 256,  256, 0, stream>>>(triples, rp, deg, col);

  if (bigws) {
    k_agg1<<<kN / 4,  256, 0, stream>>>(rp, col, featbf, comps, aggb);
    k_gemm<<<kMB,     512, 0, stream>>>(aggb, Bt, bias, out);
  } else {
    k_out_fused<<<kN / kTN, 512, 0, stream>>>(rp, col, feat, featbf, Bt,
                                              comps, bias, out);
  }
}

// Round 11
// 176.208 us; speedup vs baseline: 1.0709x; 1.0709x over previous
//
#include <hip/hip_runtime.h>

// R-GCN basis-decomposed layer, fissioned:
//   k_agg1: 1 wave/node gather+combine -> aggb bf16 (pre-swizzled rows),
//           scalar col path, 1-deep gather pipeline (round-9 proven config)
//   k_gemm: out = aggb @ BtT via mfma 16x16x32 bf16, BM=128, BK=64, 1024 thr,
//           double-buffered LDS (96 KB), counted-vmcnt(3) pipeline
// Fallback (small ws): fused kernel (swizzled-Bt reader).
//
// ws path A (~145.9 MB): featbf | Bt | aggb | deg | rp | col | blksum
// ws path B (~22.7 MB):  featbf | Bt | deg | rp | col | blksum

namespace {
constexpr int kN     = 30000;
constexpr int kR0    = 8;
constexpr int kNRel  = 16;
constexpr int kIN    = 256;
constexpr int kOUT   = 256;
constexpr int kE     = 300000;
constexpr int kNB    = 8;
constexpr int kKT    = kNB * kIN;          // 2048
constexpr int kRows  = kN * kNRel;         // 480000
constexpr int kMsgs  = 2 * kE;             // 600000
constexpr int kScanBlk  = 1024;
constexpr int kNScanBlk = (kRows + kScanBlk - 1) / kScanBlk;   // 469
constexpr int kBM    = 128;
constexpr int kMB    = (kN + kBM - 1) / kBM;   // 235 gemm blocks
constexpr int kMPadAlloc = 30016;              // aggb alloc rows; last block over-reads
                                               // 64 rows into csr region (harmless)
constexpr int kTN    = 16;                 // fused-path nodes per block
}

typedef __bf16 bf16x8 __attribute__((ext_vector_type(8)));
typedef float  f32x4  __attribute__((ext_vector_type(4)));
typedef float  f32x2  __attribute__((ext_vector_type(2)));
typedef float  f32x4v __attribute__((ext_vector_type(4)));
typedef unsigned int u32;

static __device__ __forceinline__ ushort f2bf(float x) {
  unsigned u = __float_as_uint(x);
  u += 0x7FFF + ((u >> 16) & 1);           // round-to-nearest-even
  return (ushort)(u >> 16);
}

static __device__ __forceinline__ void gload16(const void* g, void* l) {
  __builtin_amdgcn_global_load_lds(
      (const __attribute__((address_space(1))) u32*)g,
      (__attribute__((address_space(3))) u32*)l, 16, 0, 0);
}

// acc.lo += C.lo*G.lo ; acc.hi += C.lo*G.hi   (broadcast C low half)
#define PKFMA_LO(ACC, G, C) \
  asm("v_pk_fma_f32 %0, %1, %2, %0 op_sel_hi:[1,0,1]" : "+v"(ACC) : "v"(G), "v"(C))
// acc.lo += C.hi*G.lo ; acc.hi += C.hi*G.hi   (broadcast C high half)
#define PKFMA_HI(ACC, G, C) \
  asm("v_pk_fma_f32 %0, %1, %2, %0 op_sel:[0,1,0] op_sel_hi:[1,1,1]" : "+v"(ACC) : "v"(G), "v"(C))

// ---------------- prep: bf16 feature copy + degree count + Bt build (merged) ----------------

__global__ void k_prep(const float* __restrict__ f, ushort* __restrict__ fb,
                       const int* __restrict__ t, int* __restrict__ deg,
                       const float* __restrict__ bases, ushort* __restrict__ Bt) {
  int i = blockIdx.x * 256 + threadIdx.x;
  if (i < kN * kIN / 4) {
    float4 v = reinterpret_cast<const float4*>(f)[i];
    ushort4 p;
    p.x = f2bf(v.x); p.y = f2bf(v.y); p.z = f2bf(v.z); p.w = f2bf(v.w);
    reinterpret_cast<ushort4*>(fb)[i] = p;
  }
  if (i < kE) {
    int s = t[3*i], r = t[3*i+1], o = t[3*i+2];
    atomicAdd(&deg[s * kNRel + r], 1);
    atomicAdd(&deg[o * kNRel + kR0 + r], 1);
  }
  if (blockIdx.x < kKT / 16) {             // 128 blocks handle the Bt transpose
    int b  = blockIdx.x;                   // k-block [b*16, b*16+16)
    int tt = threadIdx.x;                  // 256 = output col
    char* dst = (char*)Bt + (size_t)tt * 4096;
    int xr = (tt & 7) << 4;
#pragma unroll
    for (int q = 0; q < 4; ++q) {
      int k0 = b * 16 + q * 4;
      ushort4 p;
      p.x = f2bf(bases[(size_t)(k0 + 0) * kOUT + tt]);
      p.y = f2bf(bases[(size_t)(k0 + 1) * kOUT + tt]);
      p.z = f2bf(bases[(size_t)(k0 + 2) * kOUT + tt]);
      p.w = f2bf(bases[(size_t)(k0 + 3) * kOUT + tt]);
      *reinterpret_cast<ushort4*>(dst + ((b * 32 + q * 8) ^ xr)) = p;
    }
  }
}

// ---------------- CSR build ----------------

__global__ void k_scan1(const int* __restrict__ deg, int* __restrict__ rp,
                        int* __restrict__ blksum) {
  __shared__ int s[256];
  int tid = threadIdx.x;
  int base = blockIdx.x * kScanBlk + tid * 4;
  int v0 = 0, v1 = 0, v2 = 0, v3 = 0;
  if (base + 3 < kRows) {
    v0 = deg[base]; v1 = deg[base+1]; v2 = deg[base+2]; v3 = deg[base+3];
  } else {
    if (base     < kRows) v0 = deg[base];
    if (base + 1 < kRows) v1 = deg[base+1];
    if (base + 2 < kRows) v2 = deg[base+2];
  }
  int t0 = v0, t1 = t0 + v1, t2 = t1 + v2, t3 = t2 + v3;
  s[tid] = t3;
  __syncthreads();
  for (int off = 1; off < 256; off <<= 1) {
    int x = 0;
    if (tid >= off) x = s[tid - off];
    __syncthreads();
    s[tid] += x;
    __syncthreads();
  }
  int excl = tid ? s[tid-1] : 0;
  if (base     < kRows) rp[base]   = excl;
  if (base + 1 < kRows) rp[base+1] = excl + t0;
  if (base + 2 < kRows) rp[base+2] = excl + t1;
  if (base + 3 < kRows) rp[base+3] = excl + t2;
  if (tid == 255) blksum[blockIdx.x] = s[255];
}

// merged scan2+scan3: each block reduces blksum[0..region) itself, then adds.
__global__ void k_scan3(int* __restrict__ rp, const int* __restrict__ blksum) {
  __shared__ int red[256];
  int tid = threadIdx.x;
  int B   = blockIdx.x;
  int region = (B * 256) >> 10;
  int partial = 0;
  for (int k = tid; k < region; k += 256) partial += blksum[k];
  red[tid] = partial;
  __syncthreads();
#pragma unroll
  for (int off = 128; off > 0; off >>= 1) {
    if (tid < off) red[tid] += red[tid + off];
    __syncthreads();
  }
  int base = red[0];
  int i = B * 256 + tid;
  if (i < kRows)       rp[i] += base;
  else if (i == kRows) rp[i]  = kMsgs;
}

// cursor = atomicSub on the still-live deg counts (no second memset needed)
__global__ void k_scatter(const int* __restrict__ t, const int* __restrict__ rp,
                          int* __restrict__ deg, int* __restrict__ col) {
  int m = blockIdx.x * 256 + threadIdx.x;
  if (m >= kMsgs) return;
  int e = (m < kE) ? m : m - kE;
  int s = t[3*e], r = t[3*e+1], o = t[3*e+2];
  int rr, tn, sn;
  if (m < kE) { rr = r;        tn = s; sn = o; }
  else        { rr = kR0 + r;  tn = o; sn = s; }
  int idx = tn * kNRel + rr;
  int pos = rp[idx] + (atomicSub(&deg[idx], 1) - 1);
  col[pos] = (rr << 16) | sn;
}

#define FMA4(A, S, G) \
  A.x += (S) * G.x; A.y += (S) * G.y; A.z += (S) * G.z; A.w += (S) * G.w;

// ---------------- path A stage 1: one wave per node, scalar cols, 1-deep pipeline ----------------

__global__ __launch_bounds__(256, 6)
void k_agg1(const int* __restrict__ rp, const int* __restrict__ col,
            const ushort* __restrict__ featbf, const float* __restrict__ comps,
            ushort* __restrict__ aggb) {
  __shared__ float cvb[4][17][kNB];     // per-wave coeff table, row 16 = zeros
  int wv   = threadIdx.x >> 6;
  int lane = threadIdx.x & 63;
  int node = blockIdx.x * 4 + wv;       // kN % 4 == 0

  if (lane < 17) {
    float val = 0.f;
    if (lane < kNRel) {
      int idx = node * kNRel + lane;
      int d = rp[idx + 1] - rp[idx];
      val = d > 0 ? 1.0f / (float)d : 0.f;
    }
#pragma unroll
    for (int b = 0; b < kNB; ++b)
      cvb[wv][lane][b] = comps[lane * kNB + b] * val;
  }
  __syncthreads();

  int se0 = __builtin_amdgcn_readfirstlane(rp[node * kNRel]);
  int se1 = __builtin_amdgcn_readfirstlane(rp[node * kNRel + kNRel]);

  // self-loop init (relation 16, val = 1) from bf16 features
  f32x2 accp[2 * kNB];                  // accp[2b]=ch01, accp[2b+1]=ch23 of basis b
  {
    uint2 sf = *reinterpret_cast<const uint2*>(featbf + (size_t)node * kIN + lane * 4);
    f32x2 p01, p23;
    p01.x = __uint_as_float(sf.x << 16);
    p01.y = __uint_as_float(sf.x & 0xFFFF0000u);
    p23.x = __uint_as_float(sf.y << 16);
    p23.y = __uint_as_float(sf.y & 0xFFFF0000u);
#pragma unroll
    for (int b = 0; b < kNB; ++b) {
      float cs = comps[2*kR0*kNB + b];
      accp[2*b]     = p01 * cs;
      accp[2*b + 1] = p23 * cs;
    }
  }

  const int pad = (16 << 16);           // rel slot 16 -> zero coeffs, node 0 row
  int voff = lane * 4;                  // element offset within a feature row
  const f32x4v* cvr = reinterpret_cast<const f32x4v*>(&cvb[wv][0][0]);

  auto compute = [&](const uint2* g, const int* sc) {
#pragma unroll
    for (int j = 0; j < 4; ++j) {
      int sr = sc[j] >> 16;
      f32x4v cA = cvr[sr * 2];
      f32x4v cB = cvr[sr * 2 + 1];
      f32x2 p01, p23;
      p01.x = __uint_as_float(g[j].x << 16);
      p01.y = __uint_as_float(g[j].x & 0xFFFF0000u);
      p23.x = __uint_as_float(g[j].y << 16);
      p23.y = __uint_as_float(g[j].y & 0xFFFF0000u);
      f32x2 cAl = cA.lo, cAh = cA.hi, cBl = cB.lo, cBh = cB.hi;
      PKFMA_LO(accp[0],  p01, cAl); PKFMA_LO(accp[1],  p23, cAl);   // b0
      PKFMA_HI(accp[2],  p01, cAl); PKFMA_HI(accp[3],  p23, cAl);   // b1
      PKFMA_LO(accp[4],  p01, cAh); PKFMA_LO(accp[5],  p23, cAh);   // b2
      PKFMA_HI(accp[6],  p01, cAh); PKFMA_HI(accp[7],  p23, cAh);   // b3
      PKFMA_LO(accp[8],  p01, cBl); PKFMA_LO(accp[9],  p23, cBl);   // b4
      PKFMA_HI(accp[10], p01, cBl); PKFMA_HI(accp[11], p23, cBl);   // b5
      PKFMA_LO(accp[12], p01, cBh); PKFMA_LO(accp[13], p23, cBh);   // b6
      PKFMA_HI(accp[14], p01, cBh); PKFMA_HI(accp[15], p23, cBh);   // b7
    }
  };

  // pipeline: chunk i's gathers issued in iteration i-1; computed in iteration i
  int sc0[4], sc1[4];
  uint2 g0[4];
#pragma unroll
  for (int j = 0; j < 4; ++j) {         // chunk 0 cols
    int ee = se0 + j;
    int ic = ee < se1 ? ee : 0;
    int v  = col[ic];
    sc0[j] = ee < se1 ? v : pad;
  }
#pragma unroll
  for (int j = 0; j < 4; ++j)           // chunk 0 gathers
    g0[j] = *reinterpret_cast<const uint2*>(featbf + (size_t)(sc0[j] & 0xFFFF) * kIN + voff);
#pragma unroll
  for (int j = 0; j < 4; ++j) {         // chunk 1 cols
    int ee = se0 + 4 + j;
    int ic = ee < se1 ? ee : 0;
    int v  = col[ic];
    sc1[j] = ee < se1 ? v : pad;
  }

  for (int e = se0; e + 4 < se1; e += 4) {
    uint2 g1[4];
#pragma unroll
    for (int j = 0; j < 4; ++j)         // issue NEXT chunk's gathers
      g1[j] = *reinterpret_cast<const uint2*>(featbf + (size_t)(sc1[j] & 0xFFFF) * kIN + voff);
    int sc2[4];
#pragma unroll
    for (int j = 0; j < 4; ++j) {       // cols two chunks ahead
      int ee = e + 8 + j;
      int ic = ee < se1 ? ee : 0;
      int v  = col[ic];
      sc2[j] = ee < se1 ? v : pad;
    }
    compute(g0, sc0);                   // consume PREVIOUS chunk (loads landed)
#pragma unroll
    for (int j = 0; j < 4; ++j) { g0[j] = g1[j]; sc0[j] = sc1[j]; sc1[j] = sc2[j]; }
  }
  if (se0 < se1) compute(g0, sc0);      // epilogue: last in-flight chunk

  // write bf16 row, pre-swizzled so GEMM's linear global_load_lds lands swizzled
  char* rowp = (char*)aggb + (size_t)node * 4096;
  int xr = (node & 7) << 4;
#pragma unroll
  for (int b = 0; b < kNB; ++b) {
    ushort4 p;
    p.x = f2bf(accp[2*b].x);     p.y = f2bf(accp[2*b].y);
    p.z = f2bf(accp[2*b + 1].x); p.w = f2bf(accp[2*b + 1].y);
    *reinterpret_cast<ushort4*>(rowp + ((b * 512 + lane * 8) ^ xr)) = p;
  }
}

// ---------------- path A stage 2: BM=128 MFMA GEMM, 16 waves, dbuf counted-vmcnt ----------------
// Per chunk/wave: 3 global_load_lds (48 KB / 16 waves). Loop: stage(c+1) then
// wait vmcnt(3) = chunk c's loads (issued LAST iteration) done, c+1's in flight.

__global__ __launch_bounds__(1024, 4)
void k_gemm(const ushort* __restrict__ aggb, const ushort* __restrict__ Bt,
            const float* __restrict__ bias, float* __restrict__ out) {
  __shared__ ushort Albs[2][kBM * 64];     // 2 x 16 KB, row stride 128 B (swizzled)
  __shared__ ushort Blds[2][256 * 64];     // 2 x 32 KB, row stride 128 B (swizzled)
  int tid  = threadIdx.x;
  int wv   = tid >> 6;          // 0..15
  int lane = tid & 63;
  int mh   = wv >> 2;           // 0..3 : rows [mh*32, +32)
  int nq   = wv & 3;            // 0..3 : cols [nq*64, +64)
  int l15  = lane & 15;
  int g4   = lane >> 4;
  int node0 = blockIdx.x * kBM;

  f32x4 acc[2][4];
#pragma unroll
  for (int mt = 0; mt < 2; ++mt)
#pragma unroll
    for (int nt = 0; nt < 4; ++nt) acc[mt][nt] = f32x4{0.f, 0.f, 0.f, 0.f};

  // 48 segs of 1 KB per chunk: segs 0..15 = A (16 KB), 16..47 = B (32 KB)
  auto stage = [&](int c, int buf) {
#pragma unroll
    for (int i = 0; i < 3; ++i) {
      int seg = wv * 3 + i;                       // 0..47
      if (seg < 16) {
        int lin = seg * 1024 + lane * 16;
        int row = lin >> 7;
        const char* src = (const char*)aggb + (size_t)(node0 + row) * 4096
                          + c * 128 + (lin & 127);
        gload16(src, (char*)Albs[buf] + seg * 1024);
      } else {
        int t2  = seg - 16;
        int lin = t2 * 1024 + lane * 16;
        int colr = lin >> 7;
        const char* src = (const char*)Bt + (size_t)colr * 4096
                          + c * 128 + (lin & 127);
        gload16(src, (char*)Blds[buf] + t2 * 1024);
      }
    }
  };

  stage(0, 0);
  asm volatile("s_waitcnt vmcnt(0)" ::: "memory");
  __builtin_amdgcn_s_barrier();

  int cur = 0;
  for (int c = 0; c < 32; ++c) {
    if (c + 1 < 32) {
      stage(c + 1, cur ^ 1);                       // 3 loads -> stay in flight
      asm volatile("s_waitcnt vmcnt(3)" ::: "memory");   // chunk c landed (own wave)
    } else {
      asm volatile("s_waitcnt vmcnt(0)" ::: "memory");
    }
    __builtin_amdgcn_s_barrier();                  // all waves' chunk-c loads landed
    __builtin_amdgcn_sched_barrier(0);
#pragma unroll
    for (int ks = 0; ks < 2; ++ks) {
      int kb = ks * 64 + g4 * 16;
      bf16x8 a[2], b[4];
#pragma unroll
      for (int mt = 0; mt < 2; ++mt) {
        int row = mh * 32 + mt * 16 + l15;
        a[mt] = *reinterpret_cast<const bf16x8*>(
            (const char*)Albs[cur] + row * 128 + (kb ^ ((row & 7) << 4)));
      }
#pragma unroll
      for (int nt = 0; nt < 4; ++nt) {
        int colr = nq * 64 + nt * 16 + l15;
        b[nt] = *reinterpret_cast<const bf16x8*>(
            (const char*)Blds[cur] + colr * 128 + (kb ^ ((colr & 7) << 4)));
      }
#pragma unroll
      for (int mt = 0; mt < 2; ++mt)
#pragma unroll
        for (int nt = 0; nt < 4; ++nt)
          acc[mt][nt] = __builtin_amdgcn_mfma_f32_16x16x32_bf16(a[mt], b[nt],
                                                                acc[mt][nt], 0, 0, 0);
    }
    asm volatile("s_waitcnt lgkmcnt(0)" ::: "memory");   // LDS reads of cur done
    __builtin_amdgcn_s_barrier();                  // before anyone re-stages cur
    cur ^= 1;
  }

#pragma unroll
  for (int nt = 0; nt < 4; ++nt) {
    int colo = nq * 64 + nt * 16 + l15;
    float bi = bias[colo];
#pragma unroll
    for (int mt = 0; mt < 2; ++mt) {
      int rbase = node0 + mh * 32 + mt * 16 + g4 * 4;
#pragma unroll
      for (int j = 0; j < 4; ++j) {
        int row = rbase + j;
        if (row < kN) out[(size_t)row * kOUT + colo] = acc[mt][nt][j] + bi;
      }
    }
  }
}

// ---------------- path B: fused fallback (swizzled-Bt reader) ----------------

__global__ __launch_bounds__(512, 4)
void k_out_fused(const int* __restrict__ rp, const int* __restrict__ col,
                 const float* __restrict__ feat, const ushort* __restrict__ featbf,
                 const ushort* __restrict__ Bt, const float* __restrict__ comps,
                 const float* __restrict__ bias, float* __restrict__ out) {
  __shared__ ushort aggs[kTN * kKT];
  __shared__ float  cvb[kTN][17][kNB];
  int tid  = threadIdx.x;
  int wv   = tid >> 6;
  int lane = tid & 63;
  int node0 = blockIdx.x * kTN;

  for (int q = tid; q < kTN * 17; q += 512) {
    int nl = q / 17, rl = q - nl * 17;
    float val = 0.f;
    if (rl < kNRel) {
      int idx = (node0 + nl) * kNRel + rl;
      int d = rp[idx + 1] - rp[idx];
      val = d > 0 ? 1.0f / (float)d : 0.f;
    }
#pragma unroll
    for (int b = 0; b < kNB; ++b)
      cvb[nl][rl][b] = comps[rl * kNB + b] * val;
  }
  __syncthreads();

  for (int half = 0; half < 2; ++half) {
    int nl   = (wv << 1) | half;
    int node = node0 + nl;
    int e0 = rp[node * kNRel];
    int e1 = rp[node * kNRel + kNRel];

    float4 f = *reinterpret_cast<const float4*>(feat + (size_t)node * kIN + lane * 4);
    float4 acc[kNB];
#pragma unroll
    for (int b = 0; b < kNB; ++b) {
      float cs = comps[2*kR0*kNB + b];
      acc[b].x = cs * f.x; acc[b].y = cs * f.y; acc[b].z = cs * f.z; acc[b].w = cs * f.w;
    }
    const float4* cvr = reinterpret_cast<const float4*>(&cvb[nl][0][0]);
    const int pad = (16 << 16);
    int cc[4];
#pragma unroll
    for (int j = 0; j < 4; ++j) {
      int ee = e0 + j;
      int v  = col[ee < kMsgs ? ee : kMsgs - 1];
      cc[j] = ee < e1 ? v : pad;
    }
    for (int e = e0; e < e1; e += 4) {
      uint2 g[4];
#pragma unroll
      for (int j = 0; j < 4; ++j) {
        int sn = cc[j] & 0xFFFF;
        g[j] = *reinterpret_cast<const uint2*>(featbf + (size_t)sn * kIN + lane * 4);
      }
      int rr[4];
#pragma unroll
      for (int j = 0; j < 4; ++j) rr[j] = cc[j] >> 16;
#pragma unroll
      for (int j = 0; j < 4; ++j) {
        int ee = e + 4 + j;
        int v  = col[ee < kMsgs ? ee : kMsgs - 1];
        cc[j] = ee < e1 ? v : pad;
      }
#pragma unroll
      for (int j = 0; j < 4; ++j) {
        float4 c0 = cvr[rr[j] * 2];
        float4 c1 = cvr[rr[j] * 2 + 1];
        float4 gg;
        gg.x = __uint_as_float(g[j].x << 16);
        gg.y = __uint_as_float(g[j].x & 0xFFFF0000u);
        gg.z = __uint_as_float(g[j].y << 16);
        gg.w = __uint_as_float(g[j].y & 0xFFFF0000u);
        FMA4(acc[0], c0.x, gg) FMA4(acc[1], c0.y, gg)
        FMA4(acc[2], c0.z, gg) FMA4(acc[3], c0.w, gg)
        FMA4(acc[4], c1.x, gg) FMA4(acc[5], c1.y, gg)
        FMA4(acc[6], c1.z, gg) FMA4(acc[7], c1.w, gg)
      }
    }
    int xr = (nl & 7) << 4;
#pragma unroll
    for (int b = 0; b < kNB; ++b) {
      ushort4 p;
      p.x = f2bf(acc[b].x); p.y = f2bf(acc[b].y);
      p.z = f2bf(acc[b].z); p.w = f2bf(acc[b].w);
      int byteoff = nl * 4096 + ((b * 512 + lane * 8) ^ xr);
      *reinterpret_cast<ushort4*>(reinterpret_cast<char*>(aggs) + byteoff) = p;
    }
  }
  __syncthreads();

  {
    int n  = lane & 15;
    int g4 = lane >> 4;
    const char* abase = reinterpret_cast<const char*>(aggs) + n * 4096;
    int axor = (n & 7) << 4;
#pragma unroll
    for (int t = 0; t < 2; ++t) {
      int ntile = wv + t * 8;
      float bi = bias[ntile * 16 + n];
      const char* btrow = reinterpret_cast<const char*>(Bt)
                          + (size_t)(ntile * 16 + n) * 4096;
      int bxor = (n & 7) << 4;
      f32x4 acc = {0.f, 0.f, 0.f, 0.f};
#pragma unroll 4
      for (int ks = 0; ks < kKT / 32; ++ks) {
        int kb = ks * 64 + g4 * 16;
        bf16x8 af = *reinterpret_cast<const bf16x8*>(abase + (kb ^ axor));
        bf16x8 bf = *reinterpret_cast<const bf16x8*>(btrow + (kb ^ bxor));
        acc = __builtin_amdgcn_mfma_f32_16x16x32_bf16(af, bf, acc, 0, 0, 0);
      }
#pragma unroll
      for (int j = 0; j < 4; ++j) {
        int row = g4 * 4 + j;
        out[(size_t)(node0 + row) * kOUT + ntile * 16 + n] = acc[j] + bi;
      }
    }
  }
}

// ---------------- launch ----------------

extern "C" void kernel_launch(void* const* d_in, const int* in_sizes, int n_in,
                              void* d_out, int out_size, void* d_ws, size_t ws_size,
                              hipStream_t stream) {
  const int*   triples = (const int*)  d_in[0];
  const float* feat    = (const float*)d_in[1];
  const float* bases   = (const float*)d_in[2];
  const float* comps   = (const float*)d_in[3];
  const float* bias    = (const float*)d_in[4];
  float* out = (float*)d_out;

  size_t featbf_b = (size_t)kN * kIN * 2;          // 15,360,000
  size_t bt_b     = (size_t)kOUT * kKT * 2;        // 1,048,576
  size_t aggb_b   = (size_t)kMPadAlloc * kKT * 2;  // 122,945,536
  size_t csr_b    = (size_t)(kRows + kRows + 1 + kMsgs + kNScanBlk) * 4;
  bool bigws = ws_size >= featbf_b + bt_b + aggb_b + csr_b + 1024;

  char* p = (char*)d_ws;
  ushort* featbf = (ushort*)p;            p += featbf_b;
  ushort* Bt     = (ushort*)p;            p += bt_b;
  ushort* aggb   = nullptr;
  if (bigws) { aggb = (ushort*)p;         p += aggb_b; }
  int* deg    = (int*)p;
  int* rp     = deg + kRows;
  int* col    = rp + kRows + 1;
  int* blksum = col + kMsgs;

  hipMemsetAsync(deg, 0, kRows * sizeof(int), stream);
  k_prep  <<<(kN * kIN / 4 + 255) / 256, 256, 0, stream>>>(feat, featbf, triples, deg,
                                                           bases, Bt);
  k_scan1 <<<kNScanBlk,             256, 0, stream>>>(deg, rp, blksum);
  k_scan3 <<<(kRows + 256) / 256,   256, 0, stream>>>(rp, blksum);
  k_scatter<<<(kMsgs + 255) / 256,  256, 0, stream>>>(triples, rp, deg, col);

  if (bigws) {
    k_agg1<<<kN / 4,   256, 0, stream>>>(rp, col, featbf, comps, aggb);
    k_gemm<<<kMB,     1024, 0, stream>>>(aggb, Bt, bias, out);
  } else {
    k_out_fused<<<kN / kTN, 512, 0, stream>>>(rp, col, feat, featbf, Bt,
                                              comps, bias, out);
  }
}